// Round 6
// baseline (226.768 us; speedup 1.0000x reference)
//
#include <hip/hip_runtime.h>
#include <math.h>

#define NEG_SLOPE 0.2f
#define NB1 256        // blocks for bucketing passes b1/b2
#define XROW 136       // 128 + 8 bf16 pad -> bank-conflict-free frag reads

typedef __attribute__((ext_vector_type(8))) short short8;
typedef __attribute__((ext_vector_type(4))) float floatx4;

__device__ __forceinline__ unsigned short f2bf(float f) {
    unsigned int u = __float_as_uint(f);
    u += 0x7fffu + ((u >> 16) & 1u);          // round-to-nearest-even
    return (unsigned short)(u >> 16);
}
__device__ __forceinline__ float bf2f(unsigned short b) {
    return __uint_as_float(((unsigned int)b) << 16);
}
__device__ __forceinline__ float u2fl(unsigned int u) {
    return __uint_as_float(u << 16);
}
__device__ __forceinline__ float u2fh(unsigned int u) {
    return __uint_as_float(u & 0xffff0000u);
}

// accumulate 8 bf16 feats (packed in uint4) scaled by wt into a[o..o+7]
__device__ __forceinline__ void fma8(float* a, int o, float wt, const uint4& hv) {
    a[o + 0] = fmaf(wt, u2fl(hv.x), a[o + 0]);
    a[o + 1] = fmaf(wt, u2fh(hv.x), a[o + 1]);
    a[o + 2] = fmaf(wt, u2fl(hv.y), a[o + 2]);
    a[o + 3] = fmaf(wt, u2fh(hv.y), a[o + 3]);
    a[o + 4] = fmaf(wt, u2fl(hv.z), a[o + 4]);
    a[o + 5] = fmaf(wt, u2fh(hv.z), a[o + 5]);
    a[o + 6] = fmaf(wt, u2fl(hv.w), a[o + 6]);
    a[o + 7] = fmaf(wt, u2fh(hv.w), a[o + 7]);
}

// ---------------------------------------------------------------------------
// Prep: W [k][j] fp32 -> W^T hi/lo bf16 [j][k] (error-compensated split).
// ---------------------------------------------------------------------------
__global__ __launch_bounds__(256) void prep_w_kernel(
    const float* __restrict__ W, unsigned short* __restrict__ WThi,
    unsigned short* __restrict__ WTlo)
{
    const int idx = blockIdx.x * 256 + threadIdx.x;  // j*128 + k
    const int j = idx >> 7, k = idx & 127;
    const float w = W[k * 128 + j];
    const unsigned short hi = f2bf(w);
    const unsigned short lo = f2bf(w - bf2f(hi));
    WThi[idx] = hi;
    WTlo[idx] = lo;
}

// ---------------------------------------------------------------------------
// GEMM: h_bf16 = bf16(x @ W) via 3-MFMA split, fp32 accum. Fused es/ed
// epilogue from the fp32 accumulators (head of wave wv's feats == wv).
// Layouts (HW-verified): A[m=lane&15][k=quad*8+j], B[k=quad*8+j][n=lane&15],
// D row=quad*4+reg, col=lane&15.
// ---------------------------------------------------------------------------
__global__ __launch_bounds__(256) void mfma_gemm_kernel(
    const float* __restrict__ x, const unsigned short* __restrict__ WThi,
    const unsigned short* __restrict__ WTlo, const float* __restrict__ a_src,
    const float* __restrict__ a_dst, unsigned short* __restrict__ hb,
    float* __restrict__ es, float* __restrict__ ed, int n)
{
    __shared__ unsigned short Xhi[32 * XROW];
    __shared__ unsigned short Xlo[32 * XROW];
    const int t = threadIdx.x;
    const int wv = t >> 6, lane = t & 63;
    const int l16 = lane & 15, quad = lane >> 4;
    const int node_base = blockIdx.x * 32;

    // preload B-frags (wave-invariant W^T rows) into registers
    short8 bh[4][2], bl[4][2];
    #pragma unroll
    for (int c = 0; c < 4; ++c) {
        #pragma unroll
        for (int u = 0; u < 2; ++u) {
            const int j = (wv * 2 + u) * 16 + l16;
            const int ko = c * 32 + quad * 8;
            bh[c][u] = *(const short8*)&WThi[j * 128 + ko];
            bl[c][u] = *(const short8*)&WTlo[j * 128 + ko];
        }
    }

    // stage X tile (32 nodes x 128 k) as hi/lo bf16
    for (int i = t; i < 1024; i += 256) {     // 1024 float4
        const int nd = i >> 5;
        const int k4 = i & 31;
        float4 xv = make_float4(0.f, 0.f, 0.f, 0.f);
        if (node_base + nd < n)
            xv = ((const float4*)(x + (size_t)(node_base + nd) * 128))[k4];
        const unsigned short h0 = f2bf(xv.x), h1 = f2bf(xv.y),
                             h2 = f2bf(xv.z), h3 = f2bf(xv.w);
        const unsigned short l0 = f2bf(xv.x - bf2f(h0)), l1 = f2bf(xv.y - bf2f(h1)),
                             l2 = f2bf(xv.z - bf2f(h2)), l3 = f2bf(xv.w - bf2f(h3));
        *(ushort4*)&Xhi[nd * XROW + k4 * 4] = make_ushort4(h0, h1, h2, h3);
        *(ushort4*)&Xlo[nd * XROW + k4 * 4] = make_ushort4(l0, l1, l2, l3);
    }
    __syncthreads();

    floatx4 acc[2][2] = {};
    #pragma unroll
    for (int c = 0; c < 4; ++c) {
        const int ko = c * 32 + quad * 8;
        short8 ah[2], al[2];
        #pragma unroll
        for (int r = 0; r < 2; ++r) {
            ah[r] = *(const short8*)&Xhi[(r * 16 + l16) * XROW + ko];
            al[r] = *(const short8*)&Xlo[(r * 16 + l16) * XROW + ko];
        }
        #pragma unroll
        for (int r = 0; r < 2; ++r)
        #pragma unroll
        for (int u = 0; u < 2; ++u) {
            acc[r][u] = __builtin_amdgcn_mfma_f32_16x16x32_bf16(ah[r], bl[c][u], acc[r][u], 0, 0, 0);
            acc[r][u] = __builtin_amdgcn_mfma_f32_16x16x32_bf16(al[r], bh[c][u], acc[r][u], 0, 0, 0);
            acc[r][u] = __builtin_amdgcn_mfma_f32_16x16x32_bf16(ah[r], bh[c][u], acc[r][u], 0, 0, 0);
        }
    }

    // epilogue: store bf16 h; fused es/ed from fp32 acc.
    float asv[2], adv[2];
    #pragma unroll
    for (int u = 0; u < 2; ++u) {
        const int feat = (wv * 2 + u) * 16 + l16;
        asv[u] = a_src[feat];
        adv[u] = a_dst[feat];
    }
    #pragma unroll
    for (int r = 0; r < 2; ++r) {
        #pragma unroll
        for (int u = 0; u < 2; ++u) {
            const int feat = (wv * 2 + u) * 16 + l16;
            #pragma unroll
            for (int g = 0; g < 4; ++g) {
                const int node = node_base + r * 16 + quad * 4 + g;
                if (node < n)
                    hb[(size_t)node * 128 + feat] = f2bf(acc[r][u][g]);
            }
        }
        #pragma unroll
        for (int g = 0; g < 4; ++g) {
            float ps = acc[r][0][g] * asv[0] + acc[r][1][g] * asv[1];
            float pd = acc[r][0][g] * adv[0] + acc[r][1][g] * adv[1];
            #pragma unroll
            for (int o = 8; o >= 1; o >>= 1) {
                ps += __shfl_xor(ps, o);
                pd += __shfl_xor(pd, o);
            }
            const int node = node_base + r * 16 + quad * 4 + g;
            if (l16 == 0 && node < n) {
                es[node * 4 + wv] = ps;   // head == wv
                ed[node * 4 + wv] = pd;
            }
        }
    }
}

// ---------------------------------------------------------------------------
// b1: read src+dst once; emit 32-bit packed edge (src | ldst<<16 | buck<<24)
// in original order (coalesced) + per-bucket global totals (196 atomics/blk).
// ---------------------------------------------------------------------------
__global__ __launch_bounds__(256) void b1_pack_count(
    const int* __restrict__ src, const int* __restrict__ dst,
    unsigned int* __restrict__ packed, int* __restrict__ btot,
    int e, int nbuck)
{
    __shared__ int cnt[256];
    const int t = threadIdx.x;
    cnt[t] = 0;
    __syncthreads();
    const int per = (e + NB1 - 1) / NB1;
    const int lo = blockIdx.x * per;
    const int hi = min(e, lo + per);
    for (int i = lo + t; i < hi; i += 256) {
        const int d = dst[i];
        atomicAdd(&cnt[d >> 8], 1);
        packed[i] = (unsigned int)src[i] | ((unsigned int)(d & 0xFF) << 16)
                  | ((unsigned int)(d >> 8) << 24);
    }
    __syncthreads();
    if (t < nbuck && cnt[t] > 0) atomicAdd(&btot[t], cnt[t]);
}

// ---------------------------------------------------------------------------
// s: one-block exclusive scan of 196 bucket totals -> base[], gcursor[]
// ---------------------------------------------------------------------------
__device__ __forceinline__ int wave_incl_scan(int v, int lane) {
    #pragma unroll
    for (int o = 1; o < 64; o <<= 1) {
        const int t = __shfl_up(v, o);
        if (lane >= o) v += t;
    }
    return v;
}

__global__ __launch_bounds__(256) void scan_small_kernel(
    const int* __restrict__ btot, int* __restrict__ base,
    int* __restrict__ gcursor, int nbuck, int e)
{
    __shared__ int ws[4];
    const int t = threadIdx.x;
    const int lane = t & 63;
    const int wv = t >> 6;
    const int v = (t < nbuck) ? btot[t] : 0;
    const int incl = wave_incl_scan(v, lane);
    if (lane == 63) ws[wv] = incl;
    __syncthreads();
    int wpre = 0;
    #pragma unroll
    for (int w = 0; w < 4; ++w) if (w < wv) wpre += ws[w];
    const int excl = wpre + incl - v;
    if (t < nbuck) { base[t] = excl; gcursor[t] = excl; }
    if (t == 0) base[nbuck] = e;
}

// ---------------------------------------------------------------------------
// b2: stash chunk in LDS (single global read), LDS hist, claim per-bucket
// contiguous ranges via ONE global atomic per (block,bucket), scatter packed
// (src|ldst<<16) into bucket-contiguous ebuf.
// ---------------------------------------------------------------------------
__global__ __launch_bounds__(256) void b2_scatter(
    const unsigned int* __restrict__ packed, int* __restrict__ gcursor,
    int* __restrict__ ebuf, int e, int nbuck)
{
    __shared__ int cnt[256];
    __shared__ int cur[256];
    __shared__ unsigned int stash[6272];   // >= ceil(1.6e6/256)=6250
    const int t = threadIdx.x;
    cnt[t] = 0;
    __syncthreads();
    const int per = (e + NB1 - 1) / NB1;
    const int lo = blockIdx.x * per;
    const int m = min(e, lo + per) - lo;
    for (int j = t; j < m; j += 256) {
        const unsigned int v = packed[lo + j];
        stash[j] = v;
        atomicAdd(&cnt[v >> 24], 1);
    }
    __syncthreads();
    if (t < nbuck) cur[t] = (cnt[t] > 0) ? atomicAdd(&gcursor[t], cnt[t]) : 0;
    __syncthreads();
    for (int j = t; j < m; j += 256) {
        const unsigned int v = stash[j];
        const int pos = atomicAdd(&cur[v >> 24], 1);
        ebuf[pos] = (int)(v & 0xFFFFFFu);
    }
}

// ---------------------------------------------------------------------------
// p4: per-bucket counting sort; emits offsets[] and count[] (degree).
// ---------------------------------------------------------------------------
__global__ __launch_bounds__(256) void p4_bucket_sort(
    const int* __restrict__ ebuf, const int* __restrict__ base,
    int* __restrict__ offsets, int* __restrict__ count,
    int* __restrict__ sorted_src, int n, int nbuck)
{
    __shared__ int hcnt[256], hexcl[256], cur[256];
    const int b = blockIdx.x;
    const int t = threadIdx.x;
    const int lane = t & 63;
    const int wv = t >> 6;
    const int start = base[b];
    const int end = base[b + 1];
    hcnt[t] = 0;
    __syncthreads();
    for (int i = start + t; i < end; i += 256)
        atomicAdd(&hcnt[(ebuf[i] >> 16) & 0xFF], 1);
    __syncthreads();
    if (wv == 0) {
        const int i0 = lane * 4;
        const int c0 = hcnt[i0], c1 = hcnt[i0 + 1], c2 = hcnt[i0 + 2], c3 = hcnt[i0 + 3];
        const int s = c0 + c1 + c2 + c3;
        const int incl = wave_incl_scan(s, lane);
        int ex = incl - s;
        hexcl[i0] = ex; ex += c0;
        hexcl[i0 + 1] = ex; ex += c1;
        hexcl[i0 + 2] = ex; ex += c2;
        hexcl[i0 + 3] = ex;
    }
    __syncthreads();
    {
        const int gd = b * 256 + t;
        const int o = start + hexcl[t];
        cur[t] = o;
        if (gd < n) { offsets[gd] = o; count[gd] = hcnt[t]; }
    }
    __syncthreads();
    for (int i = start + t; i < end; i += 256) {
        const int v = ebuf[i];
        const int pos = atomicAdd(&cur[(v >> 16) & 0xFF], 1);
        sorted_src[pos] = v & 0xFFFF;
    }
}

// ---------------------------------------------------------------------------
// Aggregate: one wave per destination node. 8 lanes/edge (lane owns 16
// feats, head = l8>>1 constant), 8 edges/iter, unrolled x2 -> 16 rows in
// flight per wave. Branch-free: out-of-range lanes carry s=0, w=0.
// ---------------------------------------------------------------------------
__global__ __launch_bounds__(256) void aggregate_kernel(
    const unsigned short* __restrict__ hb, const float* __restrict__ es,
    const float* __restrict__ ed, const float* __restrict__ bias,
    const int* __restrict__ offsets, const int* __restrict__ degree,
    const int* __restrict__ sorted_src, float* __restrict__ out, int n)
{
    const int lane = threadIdx.x & 63;
    const int wv = threadIdx.x >> 6;
    const int nwaves = gridDim.x * 4;
    const int l8 = lane & 7;
    const int oct = lane >> 3;
    const int f0 = l8 * 16;      // this lane's 16 output features
    const int hh = l8 >> 1;      // head of those features (constant)

    for (int node = blockIdx.x * 4 + wv; node < n; node += nwaves) {
        const int off = offsets[node];
        const int deg = degree[node];
        const float edh = ed[(size_t)node * 4 + hh];

        float a[16];
        #pragma unroll
        for (int k = 0; k < 16; ++k) a[k] = 0.f;
        float wsum = 0.f;

        for (int c0 = 0; c0 < deg; c0 += 64) {
            const int cnt = min(64, deg - c0);
            int s_l = 0;
            if (c0 + lane < deg) s_l = sorted_src[off + c0 + lane];
            const int groups = (cnt + 7) >> 3;
            for (int i = 0; i < groups; i += 2) {
                const int ci0 = 8 * i + oct;
                const int ci1 = ci0 + 8;                 // <= 63 always
                const int s0 = __shfl(s_l, ci0);
                const int s1 = __shfl(s_l, ci1);
                const float e0 = es[(size_t)s0 * 4 + hh];
                const float e1 = es[(size_t)s1 * 4 + hh];
                const uint4 hA0 = *(const uint4*)&hb[(size_t)s0 * 128 + f0];
                const uint4 hB0 = *(const uint4*)&hb[(size_t)s0 * 128 + f0 + 8];
                const uint4 hA1 = *(const uint4*)&hb[(size_t)s1 * 128 + f0];
                const uint4 hB1 = *(const uint4*)&hb[(size_t)s1 * 128 + f0 + 8];
                float lg0 = e0 + edh; lg0 = lg0 > 0.f ? lg0 : NEG_SLOPE * lg0;
                float lg1 = e1 + edh; lg1 = lg1 > 0.f ? lg1 : NEG_SLOPE * lg1;
                const float w0 = (ci0 < cnt) ? __expf(lg0) : 0.f;
                const float w1 = (ci1 < cnt) ? __expf(lg1) : 0.f;
                fma8(a, 0, w0, hA0); fma8(a, 8, w0, hB0);
                fma8(a, 0, w1, hA1); fma8(a, 8, w1, hB1);
                wsum += w0 + w1;
            }
        }
        // combine the 8 octs
        #pragma unroll
        for (int o = 8; o <= 32; o <<= 1) {
            #pragma unroll
            for (int k = 0; k < 16; ++k) a[k] += __shfl_xor(a[k], o);
            wsum += __shfl_xor(wsum, o);
        }
        if (oct == 0) {
            const float inv = 1.f / ((wsum > 0.f) ? wsum : 1.f);
            #pragma unroll
            for (int q = 0; q < 4; ++q) {
                const float4 bq = *(const float4*)(bias + f0 + q * 4);
                float4 o4;
                o4.x = a[q * 4 + 0] * inv + bq.x;
                o4.y = a[q * 4 + 1] * inv + bq.y;
                o4.z = a[q * 4 + 2] * inv + bq.z;
                o4.w = a[q * 4 + 3] * inv + bq.w;
                *(float4*)(out + (size_t)node * 128 + f0 + q * 4) = o4;
            }
        }
    }
}

// ---------------------------------------------------------------------------
extern "C" void kernel_launch(void* const* d_in, const int* in_sizes, int n_in,
                              void* d_out, int out_size, void* d_ws, size_t ws_size,
                              hipStream_t stream)
{
    const float* x      = (const float*)d_in[0];
    const float* W      = (const float*)d_in[1];
    const float* a_src  = (const float*)d_in[2];
    const float* a_dst  = (const float*)d_in[3];
    const float* bias   = (const float*)d_in[4];
    const int*   e_src  = (const int*)d_in[5];
    const int*   e_dst  = (const int*)d_in[6];
    float* out = (float*)d_out;

    const int n = in_sizes[0] / 128;             // 50000 (< 65536: src fits 16b)
    const int e = in_sizes[5];                   // 1600000
    const int nbuck = (n + 255) >> 8;            // 196 (< 256: bucket fits 8b)

    char* ws = (char*)d_ws;
    size_t o = 0;
    auto alloc = [&](size_t bytes) { void* p = ws + o; o += (bytes + 255) & ~(size_t)255; return p; };
    unsigned short* hb   = (unsigned short*)alloc((size_t)n * 128 * sizeof(unsigned short)); // 12.8 MB
    unsigned short* WThi = (unsigned short*)alloc(128 * 128 * sizeof(unsigned short));
    unsigned short* WTlo = (unsigned short*)alloc(128 * 128 * sizeof(unsigned short));
    float* es      = (float*)alloc((size_t)n * 4 * sizeof(float));
    float* ed      = (float*)alloc((size_t)n * 4 * sizeof(float));
    unsigned int* packed = (unsigned int*)alloc((size_t)e * sizeof(unsigned int)); // 6.4 MB
    int* ebuf      = (int*)alloc((size_t)e * sizeof(int));                         // 6.4 MB
    int* sortedsrc = (int*)alloc((size_t)e * sizeof(int));                         // 6.4 MB
    int* btot      = (int*)alloc((size_t)(nbuck) * sizeof(int));
    int* base      = (int*)alloc((size_t)(nbuck + 1) * sizeof(int));
    int* gcursor   = (int*)alloc((size_t)(nbuck) * sizeof(int));
    int* offsets   = (int*)alloc((size_t)n * sizeof(int));
    int* count     = (int*)alloc((size_t)n * sizeof(int));
    (void)ws_size; (void)n_in; (void)out_size;

    (void)hipMemsetAsync(btot, 0, (size_t)nbuck * sizeof(int), stream);

    prep_w_kernel<<<64, 256, 0, stream>>>(W, WThi, WTlo);
    mfma_gemm_kernel<<<(n + 31) / 32, 256, 0, stream>>>(x, WThi, WTlo, a_src, a_dst,
                                                        hb, es, ed, n);
    b1_pack_count<<<NB1, 256, 0, stream>>>(e_src, e_dst, packed, btot, e, nbuck);
    scan_small_kernel<<<1, 256, 0, stream>>>(btot, base, gcursor, nbuck, e);
    b2_scatter<<<NB1, 256, 0, stream>>>(packed, gcursor, ebuf, e, nbuck);
    p4_bucket_sort<<<nbuck, 256, 0, stream>>>(ebuf, base, offsets, count,
                                              sortedsrc, n, nbuck);
    aggregate_kernel<<<(n + 3) / 4, 256, 0, stream>>>(hb, es, ed, bias, offsets,
                                                      count, sortedsrc, out, n);
}

// Round 7
// 197.327 us; speedup vs baseline: 1.1492x; 1.1492x over previous
//
#include <hip/hip_runtime.h>
#include <math.h>

#define NEG_SLOPE 0.2f
#define NB1 256          // blocks for bucket_scatter
#define XROW 136         // 128 + 8 bf16 pad -> bank-conflict-free frag reads
#define BSHIFT 5         // bucket = dst >> 5  (32 nodes per bucket)
#define BNODES 32
#define CAP 2048         // per-bucket ebuf capacity (mean 1024, sigma ~32)

typedef __attribute__((ext_vector_type(8))) short short8;
typedef __attribute__((ext_vector_type(4))) float floatx4;

__device__ __forceinline__ unsigned short f2bf(float f) {
    unsigned int u = __float_as_uint(f);
    u += 0x7fffu + ((u >> 16) & 1u);          // round-to-nearest-even
    return (unsigned short)(u >> 16);
}
__device__ __forceinline__ float bf2f(unsigned short b) {
    return __uint_as_float(((unsigned int)b) << 16);
}
__device__ __forceinline__ float u2fl(unsigned int u) {
    return __uint_as_float(u << 16);
}
__device__ __forceinline__ float u2fh(unsigned int u) {
    return __uint_as_float(u & 0xffff0000u);
}

// accumulate 8 bf16 feats (packed in uint4) scaled by wt into a[o..o+7]
__device__ __forceinline__ void fma8(float* a, int o, float wt, const uint4& hv) {
    a[o + 0] = fmaf(wt, u2fl(hv.x), a[o + 0]);
    a[o + 1] = fmaf(wt, u2fh(hv.x), a[o + 1]);
    a[o + 2] = fmaf(wt, u2fl(hv.y), a[o + 2]);
    a[o + 3] = fmaf(wt, u2fh(hv.y), a[o + 3]);
    a[o + 4] = fmaf(wt, u2fl(hv.z), a[o + 4]);
    a[o + 5] = fmaf(wt, u2fh(hv.z), a[o + 5]);
    a[o + 6] = fmaf(wt, u2fl(hv.w), a[o + 6]);
    a[o + 7] = fmaf(wt, u2fh(hv.w), a[o + 7]);
}

// ---------------------------------------------------------------------------
// Prep: W [k][j] fp32 -> W^T hi/lo bf16 [j][k] (error-compensated split);
// also initializes the per-bucket global cursors gcur[b] = b*CAP.
// ---------------------------------------------------------------------------
__global__ __launch_bounds__(256) void prep_w_kernel(
    const float* __restrict__ W, unsigned short* __restrict__ WThi,
    unsigned short* __restrict__ WTlo, int* __restrict__ gcur, int nbuck)
{
    const int idx = blockIdx.x * 256 + threadIdx.x;  // j*128 + k
    const int j = idx >> 7, k = idx & 127;
    const float w = W[k * 128 + j];
    const unsigned short hi = f2bf(w);
    const unsigned short lo = f2bf(w - bf2f(hi));
    WThi[idx] = hi;
    WTlo[idx] = lo;
    if (idx < nbuck) gcur[idx] = idx * CAP;
}

// ---------------------------------------------------------------------------
// GEMM: h_bf16 = bf16(x @ W) via 3-MFMA split, fp32 accum. Fused es/ed
// epilogue from the fp32 accumulators (head of wave wv's feats == wv).
// Layouts (HW-verified): A[m=lane&15][k=quad*8+j], B[k=quad*8+j][n=lane&15],
// D row=quad*4+reg, col=lane&15.
// ---------------------------------------------------------------------------
__global__ __launch_bounds__(256) void mfma_gemm_kernel(
    const float* __restrict__ x, const unsigned short* __restrict__ WThi,
    const unsigned short* __restrict__ WTlo, const float* __restrict__ a_src,
    const float* __restrict__ a_dst, unsigned short* __restrict__ hb,
    float* __restrict__ es, float* __restrict__ ed, int n)
{
    __shared__ unsigned short Xhi[32 * XROW];
    __shared__ unsigned short Xlo[32 * XROW];
    const int t = threadIdx.x;
    const int wv = t >> 6, lane = t & 63;
    const int l16 = lane & 15, quad = lane >> 4;
    const int node_base = blockIdx.x * 32;

    // preload B-frags (wave-invariant W^T rows) into registers
    short8 bh[4][2], bl[4][2];
    #pragma unroll
    for (int c = 0; c < 4; ++c) {
        #pragma unroll
        for (int u = 0; u < 2; ++u) {
            const int j = (wv * 2 + u) * 16 + l16;
            const int ko = c * 32 + quad * 8;
            bh[c][u] = *(const short8*)&WThi[j * 128 + ko];
            bl[c][u] = *(const short8*)&WTlo[j * 128 + ko];
        }
    }

    // stage X tile (32 nodes x 128 k) as hi/lo bf16
    for (int i = t; i < 1024; i += 256) {     // 1024 float4
        const int nd = i >> 5;
        const int k4 = i & 31;
        float4 xv = make_float4(0.f, 0.f, 0.f, 0.f);
        if (node_base + nd < n)
            xv = ((const float4*)(x + (size_t)(node_base + nd) * 128))[k4];
        const unsigned short h0 = f2bf(xv.x), h1 = f2bf(xv.y),
                             h2 = f2bf(xv.z), h3 = f2bf(xv.w);
        const unsigned short l0 = f2bf(xv.x - bf2f(h0)), l1 = f2bf(xv.y - bf2f(h1)),
                             l2 = f2bf(xv.z - bf2f(h2)), l3 = f2bf(xv.w - bf2f(h3));
        *(ushort4*)&Xhi[nd * XROW + k4 * 4] = make_ushort4(h0, h1, h2, h3);
        *(ushort4*)&Xlo[nd * XROW + k4 * 4] = make_ushort4(l0, l1, l2, l3);
    }
    __syncthreads();

    floatx4 acc[2][2] = {};
    #pragma unroll
    for (int c = 0; c < 4; ++c) {
        const int ko = c * 32 + quad * 8;
        short8 ah[2], al[2];
        #pragma unroll
        for (int r = 0; r < 2; ++r) {
            ah[r] = *(const short8*)&Xhi[(r * 16 + l16) * XROW + ko];
            al[r] = *(const short8*)&Xlo[(r * 16 + l16) * XROW + ko];
        }
        #pragma unroll
        for (int r = 0; r < 2; ++r)
        #pragma unroll
        for (int u = 0; u < 2; ++u) {
            acc[r][u] = __builtin_amdgcn_mfma_f32_16x16x32_bf16(ah[r], bl[c][u], acc[r][u], 0, 0, 0);
            acc[r][u] = __builtin_amdgcn_mfma_f32_16x16x32_bf16(al[r], bh[c][u], acc[r][u], 0, 0, 0);
            acc[r][u] = __builtin_amdgcn_mfma_f32_16x16x32_bf16(ah[r], bh[c][u], acc[r][u], 0, 0, 0);
        }
    }

    // epilogue: store bf16 h; fused es/ed from fp32 acc.
    float asv[2], adv[2];
    #pragma unroll
    for (int u = 0; u < 2; ++u) {
        const int feat = (wv * 2 + u) * 16 + l16;
        asv[u] = a_src[feat];
        adv[u] = a_dst[feat];
    }
    #pragma unroll
    for (int r = 0; r < 2; ++r) {
        #pragma unroll
        for (int u = 0; u < 2; ++u) {
            const int feat = (wv * 2 + u) * 16 + l16;
            #pragma unroll
            for (int g = 0; g < 4; ++g) {
                const int node = node_base + r * 16 + quad * 4 + g;
                if (node < n)
                    hb[(size_t)node * 128 + feat] = f2bf(acc[r][u][g]);
            }
        }
        #pragma unroll
        for (int g = 0; g < 4; ++g) {
            float ps = acc[r][0][g] * asv[0] + acc[r][1][g] * asv[1];
            float pd = acc[r][0][g] * adv[0] + acc[r][1][g] * adv[1];
            #pragma unroll
            for (int o = 8; o >= 1; o >>= 1) {
                ps += __shfl_xor(ps, o);
                pd += __shfl_xor(pd, o);
            }
            const int node = node_base + r * 16 + quad * 4 + g;
            if (l16 == 0 && node < n) {
                es[node * 4 + wv] = ps;   // head == wv
                ed[node * 4 + wv] = pd;
            }
        }
    }
}

// ---------------------------------------------------------------------------
// bucket_scatter: single pass over src/dst. Stash packed edges in LDS,
// LDS-count per bucket, claim contiguous range in the bucket's fixed-CAP
// region with ONE global atomic per (block,bucket), scatter (src|ldst<<16)
// into ebuf. No scan kernel needed (fixed-capacity regions).
// Pack: src[0:16) | ldst[16:21) | bucket[21:32).
// ---------------------------------------------------------------------------
__global__ __launch_bounds__(256) void bucket_scatter(
    const int* __restrict__ src, const int* __restrict__ dst,
    int* __restrict__ gcur, int* __restrict__ ebuf, int e, int nbuck)
{
    __shared__ unsigned int stash[6272];   // >= ceil(1.6e6/256)=6250
    __shared__ int cnt[1600];
    __shared__ int cur[1600];
    const int t = threadIdx.x;
    for (int b = t; b < nbuck; b += 256) cnt[b] = 0;
    __syncthreads();
    const int per = (e + NB1 - 1) / NB1;
    const int lo = blockIdx.x * per;
    const int m = min(e, lo + per) - lo;
    for (int j = t; j < m; j += 256) {
        const int d = dst[lo + j];
        const unsigned int v = (unsigned int)src[lo + j]
                             | ((unsigned int)(d & (BNODES - 1)) << 16)
                             | ((unsigned int)(d >> BSHIFT) << 21);
        stash[j] = v;
        atomicAdd(&cnt[d >> BSHIFT], 1);
    }
    __syncthreads();
    for (int b = t; b < nbuck; b += 256) {
        const int c = cnt[b];
        if (c > 0) cur[b] = atomicAdd(&gcur[b], c);
    }
    __syncthreads();
    for (int j = t; j < m; j += 256) {
        const unsigned int v = stash[j];
        const int pos = atomicAdd(&cur[v >> 21], 1);
        ebuf[pos] = (int)(v & 0x1FFFFFu);
    }
}

// ---------------------------------------------------------------------------
// sort_agg: one block per bucket (32 nodes). In-LDS counting sort of the
// bucket's edges (ebuf read twice, 2nd hits L1), then wave wv aggregates
// nodes wv*8..wv*8+7 sequentially: 8 lanes/edge (lane owns 16 feats),
// 16 edges in flight per wave. No global sorted_src / offsets / degree.
// ---------------------------------------------------------------------------
__global__ __launch_bounds__(256) void sort_agg_kernel(
    const unsigned short* __restrict__ hb, const float* __restrict__ es,
    const float* __restrict__ ed, const float* __restrict__ bias,
    const int* __restrict__ gcur, const int* __restrict__ ebuf,
    float* __restrict__ out, int n)
{
    __shared__ unsigned short esort[CAP];
    __shared__ int hist[BNODES], hexcl[BNODES], cur[BNODES];
    const int b = blockIdx.x;
    const int t = threadIdx.x;
    const int lane = t & 63;
    const int wv = t >> 6;
    const int l8 = lane & 7;
    const int oct = lane >> 3;
    const int f0 = l8 * 16;      // this lane's 16 output features
    const int hh = l8 >> 1;      // head of those features (constant)

    const int start = b * CAP;
    const int end = gcur[b];     // start + bucket count

    if (t < BNODES) hist[t] = 0;
    __syncthreads();
    for (int i = start + t; i < end; i += 256)
        atomicAdd(&hist[(ebuf[i] >> 16) & (BNODES - 1)], 1);
    __syncthreads();
    if (wv == 0) {
        const int v = (lane < BNODES) ? hist[lane] : 0;
        int incl = v;
        #pragma unroll
        for (int o = 1; o < BNODES; o <<= 1) {
            const int tt = __shfl_up(incl, o);
            if (lane >= o) incl += tt;
        }
        if (lane < BNODES) { hexcl[lane] = incl - v; cur[lane] = incl - v; }
    }
    __syncthreads();
    for (int i = start + t; i < end; i += 256) {
        const int v = ebuf[i];
        const int pos = atomicAdd(&cur[(v >> 16) & (BNODES - 1)], 1);
        esort[pos] = (unsigned short)(v & 0xFFFF);
    }
    __syncthreads();

    // aggregation: wave wv owns nodes wv*8 .. wv*8+7 (sequential)
    for (int j = 0; j < 8; ++j) {
        const int nd = wv * 8 + j;
        const int node = b * BNODES + nd;
        if (node >= n) break;
        const int off = hexcl[nd];
        const int deg = hist[nd];
        const float edh = ed[(size_t)node * 4 + hh];

        float a[16];
        #pragma unroll
        for (int k = 0; k < 16; ++k) a[k] = 0.f;
        float wsum = 0.f;

        for (int c0 = 0; c0 < deg; c0 += 16) {
            const int ci0 = c0 + oct;
            const int ci1 = ci0 + 8;
            const int dm = deg - 1;
            const int s0 = esort[off + min(ci0, dm)];
            const int s1 = esort[off + min(ci1, dm)];
            const float e0 = es[(size_t)s0 * 4 + hh];
            const float e1 = es[(size_t)s1 * 4 + hh];
            const uint4 hA0 = *(const uint4*)&hb[(size_t)s0 * 128 + f0];
            const uint4 hB0 = *(const uint4*)&hb[(size_t)s0 * 128 + f0 + 8];
            const uint4 hA1 = *(const uint4*)&hb[(size_t)s1 * 128 + f0];
            const uint4 hB1 = *(const uint4*)&hb[(size_t)s1 * 128 + f0 + 8];
            float lg0 = e0 + edh; lg0 = lg0 > 0.f ? lg0 : NEG_SLOPE * lg0;
            float lg1 = e1 + edh; lg1 = lg1 > 0.f ? lg1 : NEG_SLOPE * lg1;
            const float w0 = (ci0 < deg) ? __expf(lg0) : 0.f;
            const float w1 = (ci1 < deg) ? __expf(lg1) : 0.f;
            fma8(a, 0, w0, hA0); fma8(a, 8, w0, hB0);
            fma8(a, 0, w1, hA1); fma8(a, 8, w1, hB1);
            wsum += w0 + w1;
        }
        // combine the 8 octs
        #pragma unroll
        for (int o = 8; o <= 32; o <<= 1) {
            #pragma unroll
            for (int k = 0; k < 16; ++k) a[k] += __shfl_xor(a[k], o);
            wsum += __shfl_xor(wsum, o);
        }
        if (oct == 0) {
            const float inv = 1.f / ((wsum > 0.f) ? wsum : 1.f);
            #pragma unroll
            for (int q = 0; q < 4; ++q) {
                const float4 bq = *(const float4*)(bias + f0 + q * 4);
                float4 o4;
                o4.x = a[q * 4 + 0] * inv + bq.x;
                o4.y = a[q * 4 + 1] * inv + bq.y;
                o4.z = a[q * 4 + 2] * inv + bq.z;
                o4.w = a[q * 4 + 3] * inv + bq.w;
                *(float4*)(out + (size_t)node * 128 + f0 + q * 4) = o4;
            }
        }
    }
}

// ---------------------------------------------------------------------------
extern "C" void kernel_launch(void* const* d_in, const int* in_sizes, int n_in,
                              void* d_out, int out_size, void* d_ws, size_t ws_size,
                              hipStream_t stream)
{
    const float* x      = (const float*)d_in[0];
    const float* W      = (const float*)d_in[1];
    const float* a_src  = (const float*)d_in[2];
    const float* a_dst  = (const float*)d_in[3];
    const float* bias   = (const float*)d_in[4];
    const int*   e_src  = (const int*)d_in[5];
    const int*   e_dst  = (const int*)d_in[6];
    float* out = (float*)d_out;

    const int n = in_sizes[0] / 128;             // 50000 (< 65536: src fits 16b)
    const int e = in_sizes[5];                   // 1600000
    const int nbuck = (n + BNODES - 1) >> BSHIFT; // 1563 (< 2048: fits 11b)

    char* ws = (char*)d_ws;
    size_t o = 0;
    auto alloc = [&](size_t bytes) { void* p = ws + o; o += (bytes + 255) & ~(size_t)255; return p; };
    unsigned short* hb   = (unsigned short*)alloc((size_t)n * 128 * sizeof(unsigned short)); // 12.8 MB
    unsigned short* WThi = (unsigned short*)alloc(128 * 128 * sizeof(unsigned short));
    unsigned short* WTlo = (unsigned short*)alloc(128 * 128 * sizeof(unsigned short));
    float* es      = (float*)alloc((size_t)n * 4 * sizeof(float));
    float* ed      = (float*)alloc((size_t)n * 4 * sizeof(float));
    int* gcur      = (int*)alloc((size_t)nbuck * sizeof(int));
    int* ebuf      = (int*)alloc((size_t)nbuck * CAP * sizeof(int));   // 12.8 MB
    (void)ws_size; (void)n_in; (void)out_size;

    prep_w_kernel<<<64, 256, 0, stream>>>(W, WThi, WTlo, gcur, nbuck);
    mfma_gemm_kernel<<<(n + 31) / 32, 256, 0, stream>>>(x, WThi, WTlo, a_src, a_dst,
                                                        hb, es, ed, n);
    bucket_scatter<<<NB1, 256, 0, stream>>>(e_src, e_dst, gcur, ebuf, e, nbuck);
    sort_agg_kernel<<<nbuck, 256, 0, stream>>>(hb, es, ed, bias, gcur, ebuf, out, n);
}